// Round 1
// 2084.588 us; speedup vs baseline: 1.1682x; 1.1682x over previous
//
#include <hip/hip_runtime.h>
#include <hip/hip_bf16.h>

#define NE 8
#define HID 2048
#define INTER 5504
#define TOK 16384
#define TE 2048  // tokens per expert

typedef __bf16 bf16x8 __attribute__((ext_vector_type(8)));
typedef float f32x4 __attribute__((ext_vector_type(4)));

__device__ __forceinline__ void async_copy16(const void* g, void* l) {
    __builtin_amdgcn_global_load_lds(
        (const __attribute__((address_space(1))) void*)g,
        (__attribute__((address_space(3))) void*)l,
        16, 0, 0);
}

// XOR swizzle on 16B-chunk index: involutive (bits 3..5 unchanged).
// Same formula as the verified previous kernel (measured 0 bank conflicts).
__device__ __forceinline__ int chunk_swz(int q) { return q ^ ((q >> 3) & 7); }

// Raw barrier WITHOUT the vmcnt(0)/lgkmcnt(0) drain that __syncthreads implies.
// Empty asm memory clobbers pin memory-op ordering around it.
__device__ __forceinline__ void block_barrier() {
    asm volatile("" ::: "memory");
    __builtin_amdgcn_s_barrier();
    asm volatile("" ::: "memory");
}

// ---------------- cast x: fp32 -> bf16, vectorized ----------------
struct alignas(8) bf4 { __hip_bfloat162 a, b; };

__global__ void cast_x_kernel(const float* __restrict__ in, __hip_bfloat16* __restrict__ out) {
    size_t i = (size_t)blockIdx.x * blockDim.x + threadIdx.x;  // one float4 per thread
    float4 v = reinterpret_cast<const float4*>(in)[i];
    bf4 p;
    p.a.x = __float2bfloat16(v.x);
    p.a.y = __float2bfloat16(v.y);
    p.b.x = __float2bfloat16(v.z);
    p.b.y = __float2bfloat16(v.w);
    reinterpret_cast<bf4*>(out)[i] = p;
}

// ---------------- transpose + cast: fp32 [E][R][C] -> bf16 [E][C][R] ----------------
// 64(R) x 128(C) tile. Trick: pack bf16 of rows (2rp, 2rp+1) into one dword at load
// time -> the LDS transpose happens at dword granularity. Pad 129 -> conflict-free.
// Output: 16B uint4 stores, 128B contiguous per out-row.
__global__ __launch_bounds__(256) void tcast2_kernel(const float* __restrict__ in,
                                                     __hip_bfloat16* __restrict__ out,
                                                     int R, int C) {
    __shared__ unsigned int D[32][129];
    const int e = blockIdx.z;
    const int r0 = blockIdx.y * 64, c0 = blockIdx.x * 128;
    const float* src = in + (size_t)e * R * C;
    __hip_bfloat16* dst = out + (size_t)e * R * C;
    const int tid = threadIdx.x;

#pragma unroll
    for (int it = 0; it < 16; ++it) {
        const int idx = tid + it * 256;    // 0..4095 = 32 row-pairs x 128 cols
        const int rp = idx >> 7, c = idx & 127;
        const float lo = src[(size_t)(r0 + 2 * rp) * C + (c0 + c)];
        const float hi = src[(size_t)(r0 + 2 * rp + 1) * C + (c0 + c)];
        const unsigned short a = __builtin_bit_cast(unsigned short, __float2bfloat16(lo));
        const unsigned short b = __builtin_bit_cast(unsigned short, __float2bfloat16(hi));
        D[rp][c] = (unsigned)a | ((unsigned)b << 16);
    }
    __syncthreads();
#pragma unroll
    for (int it = 0; it < 4; ++it) {
        const int idx = tid + it * 256;    // 0..1023 = 128 out-rows x 8 chunks
        const int c = idx >> 3, q = idx & 7;
        uint4 w;
        w.x = D[4 * q + 0][c];
        w.y = D[4 * q + 1][c];
        w.z = D[4 * q + 2][c];
        w.w = D[4 * q + 3][c];
        *reinterpret_cast<uint4*>(dst + (size_t)(c0 + c) * R + r0 + q * 8) = w;
    }
}

// ---------------- GEMM1: x @ {gate,up} fused + SwiGLU -> h (bf16) ----------------
// Deep-pipelined schedule: BM=256, BN=128 (dual-B gate+up), BK=32, 8 waves (2M x 4N),
// 4-slot LDS ring (128 KiB), counted vmcnt(6) once per K-tile (never 0), stage-issue
// 2 K-tiles ahead, 2 phases/K-tile with setprio-wrapped 16-MFMA clusters.
// LDS buffer b: chunks [b*2048, b*2048+1024) = A rows 0..255; [+1024, +2048) = B rows:
// 0..127 gate n-rows, 128..255 up n-rows.
__global__ __launch_bounds__(512, 2) void gemm1_swiglu_kernel(
    const __hip_bfloat16* __restrict__ xb,
    const __hip_bfloat16* __restrict__ gwt,
    const __hip_bfloat16* __restrict__ uwt,
    __hip_bfloat16* __restrict__ hout) {
    // bijective XCD swizzle: 2752 blocks = 8 XCD x 344 -> one expert per XCD
    const int lin = blockIdx.x + ((blockIdx.y + blockIdx.z * 43) << 3);
    const int swz = (lin & 7) * 344 + (lin >> 3);
    const int e = swz / 344;
    const int rem = swz - e * 344;
    const int nt = rem >> 3, mt = rem & 7;
    const int m0 = mt * 256, n0 = nt * 128;

    const __hip_bfloat16* A = xb + (size_t)(e * TE + m0) * HID;
    const __hip_bfloat16* Bg = gwt + (size_t)e * INTER * HID + (size_t)n0 * HID;
    const __hip_bfloat16* Bu = uwt + (size_t)e * INTER * HID + (size_t)n0 * HID;

    __shared__ __align__(16) __hip_bfloat16 S[4 * 2048 * 8];  // 128 KiB, 4 ring slots

    const int tid = threadIdx.x;
    const int wave = tid >> 6, lane = tid & 63;
    const int wmh = (wave >> 2) * 128;  // wave M offset (0/128)
    const int wnq = (wave & 3) * 32;    // wave N offset (0..96)
    const int qd = lane >> 4, ln = lane & 15;

    // staging precompute: phase p stages physical chunk c = p*512+tid (A and B regions)
    const __hip_bfloat16* aSrc[2];
    const __hip_bfloat16* bSrc[2];
#pragma unroll
    for (int p = 0; p < 2; ++p) {
        const int c = p * 512 + tid;
        const int id = chunk_swz(c);
        const int row = id >> 2, col = (id & 3) * 8;
        aSrc[p] = A + (size_t)row * HID + col;
        bSrc[p] = (row < 128 ? Bg + (size_t)row * HID
                             : Bu + (size_t)(row - 128) * HID) + col;
    }

    // frag read physical chunk offsets (within a ring slot)
    int pA[8], pG[2], pU[2];
#pragma unroll
    for (int mi = 0; mi < 8; ++mi) pA[mi] = chunk_swz((wmh + mi * 16 + ln) * 4 + qd);
#pragma unroll
    for (int ni = 0; ni < 2; ++ni) {
        pG[ni] = 1024 + chunk_swz((wnq + ni * 16 + ln) * 4 + qd);
        pU[ni] = 1024 + chunk_swz((128 + wnq + ni * 16 + ln) * 4 + qd);
    }

    f32x4 accg[8][2], accu[8][2];
    const f32x4 z4 = {0.f, 0.f, 0.f, 0.f};
#pragma unroll
    for (int mi = 0; mi < 8; ++mi)
#pragma unroll
        for (int ni = 0; ni < 2; ++ni) { accg[mi][ni] = z4; accu[mi][ni] = z4; }

    const int NT = HID / 32;  // 64 K-tiles
    // prologue: stage K-tiles 0 and 1 (8 issues/wave, in FIFO order)
#pragma unroll
    for (int t = 0; t < 2; ++t)
#pragma unroll
        for (int p = 0; p < 2; ++p) {
            const int c = p * 512 + tid;
            async_copy16(aSrc[p] + t * 32, (void*)(S + (size_t)(t * 2048 + c) * 8));
            async_copy16(bSrc[p] + t * 32, (void*)(S + (size_t)(t * 2048 + 1024 + c) * 8));
        }

    for (int t = 0; t < NT; ++t) {
        const __hip_bfloat16* Sb = S + (size_t)((t & 3) * 2048) * 8;
        const int buf2 = ((t + 2) & 3) * 2048;
        const int k2 = (t + 2 < NT ? t + 2 : t + 2 - NT) * 32;  // wrapped dummy at tail

        // ---- phase 0: issue stage (t+2, half 0); wait tile t; MFMA mi 0..3 ----
        {
            const int c = tid;
            async_copy16(aSrc[0] + k2, (void*)(S + (size_t)(buf2 + c) * 8));
            async_copy16(bSrc[0] + k2, (void*)(S + (size_t)(buf2 + 1024 + c) * 8));
        }
        // outstanding (FIFO): <= {t rest, t+1: 4, t+2: 2}; vmcnt(6) => tile t landed
        asm volatile("s_waitcnt vmcnt(6)" ::: "memory");
        block_barrier();

        bf16x8 bg[2], bu[2], af[4];
#pragma unroll
        for (int ni = 0; ni < 2; ++ni) {
            bg[ni] = *reinterpret_cast<const bf16x8*>(Sb + (size_t)pG[ni] * 8);
            bu[ni] = *reinterpret_cast<const bf16x8*>(Sb + (size_t)pU[ni] * 8);
        }
#pragma unroll
        for (int mi = 0; mi < 4; ++mi)
            af[mi] = *reinterpret_cast<const bf16x8*>(Sb + (size_t)pA[mi] * 8);

        __builtin_amdgcn_s_setprio(1);
#pragma unroll
        for (int mi = 0; mi < 4; ++mi)
#pragma unroll
            for (int ni = 0; ni < 2; ++ni) {
                accg[mi][ni] = __builtin_amdgcn_mfma_f32_16x16x32_bf16(af[mi], bg[ni], accg[mi][ni], 0, 0, 0);
                accu[mi][ni] = __builtin_amdgcn_mfma_f32_16x16x32_bf16(af[mi], bu[ni], accu[mi][ni], 0, 0, 0);
            }
        __builtin_amdgcn_s_setprio(0);
        block_barrier();

        // ---- phase 1: issue stage (t+2, half 1); MFMA mi 4..7 ----
        {
            const int c = 512 + tid;
            async_copy16(aSrc[1] + k2, (void*)(S + (size_t)(buf2 + c) * 8));
            async_copy16(bSrc[1] + k2, (void*)(S + (size_t)(buf2 + 1024 + c) * 8));
        }
        bf16x8 af2[4];
#pragma unroll
        for (int mi = 0; mi < 4; ++mi)
            af2[mi] = *reinterpret_cast<const bf16x8*>(Sb + (size_t)pA[mi + 4] * 8);

        __builtin_amdgcn_s_setprio(1);
#pragma unroll
        for (int mi = 0; mi < 4; ++mi)
#pragma unroll
            for (int ni = 0; ni < 2; ++ni) {
                accg[mi + 4][ni] = __builtin_amdgcn_mfma_f32_16x16x32_bf16(af2[mi], bg[ni], accg[mi + 4][ni], 0, 0, 0);
                accu[mi + 4][ni] = __builtin_amdgcn_mfma_f32_16x16x32_bf16(af2[mi], bu[ni], accu[mi + 4][ni], 0, 0, 0);
            }
        __builtin_amdgcn_s_setprio(0);
        block_barrier();
    }

    // epilogue: SwiGLU, write bf16 h.  C/D layout: col=lane&15, row=(lane>>4)*4+r
    __hip_bfloat16* H = hout + (size_t)(e * TE + m0 + wmh) * INTER + n0 + wnq;
#pragma unroll
    for (int mi = 0; mi < 8; ++mi)
#pragma unroll
        for (int ni = 0; ni < 2; ++ni)
#pragma unroll
            for (int r = 0; r < 4; ++r) {
                const int rr = mi * 16 + qd * 4 + r;
                const int cc = ni * 16 + ln;
                const float g = accg[mi][ni][r];
                const float u = accu[mi][ni][r];
                const float s = g / (1.0f + __expf(-g));
                H[(size_t)rr * INTER + cc] = __float2bfloat16(s * u);
            }
}

// ---------------- GEMM2: h @ down -> out (fp32) ----------------
// Same pipelined schedule: BM=256, BN=256, BK=32, 8 waves, per-wave 128x64.
__global__ __launch_bounds__(512, 2) void gemm2_kernel(
    const __hip_bfloat16* __restrict__ hb,
    const __hip_bfloat16* __restrict__ dwt,
    float* __restrict__ out) {
    // bijective XCD swizzle: 512 blocks = 8 XCD x 64 -> one expert per XCD
    const int lin = blockIdx.x + ((blockIdx.y + (blockIdx.z << 3)) << 3);
    const int swz = (lin & 7) * 64 + (lin >> 3);
    const int e = swz >> 6;
    const int rem = swz & 63;
    const int nt = rem >> 3, mt = rem & 7;
    const int m0 = mt * 256, n0 = nt * 256;

    const __hip_bfloat16* A = hb + (size_t)(e * TE + m0) * INTER;
    const __hip_bfloat16* B = dwt + (size_t)e * HID * INTER + (size_t)n0 * INTER;

    __shared__ __align__(16) __hip_bfloat16 S[4 * 2048 * 8];  // 128 KiB

    const int tid = threadIdx.x;
    const int wave = tid >> 6, lane = tid & 63;
    const int wmh = (wave >> 2) * 128;
    const int wnq = (wave & 3) * 64;
    const int qd = lane >> 4, ln = lane & 15;

    const __hip_bfloat16* aSrc[2];
    const __hip_bfloat16* bSrc[2];
#pragma unroll
    for (int p = 0; p < 2; ++p) {
        const int c = p * 512 + tid;
        const int id = chunk_swz(c);
        const int row = id >> 2, col = (id & 3) * 8;
        aSrc[p] = A + (size_t)row * INTER + col;
        bSrc[p] = B + (size_t)row * INTER + col;
    }

    int pA[8], pB[4];
#pragma unroll
    for (int mi = 0; mi < 8; ++mi) pA[mi] = chunk_swz((wmh + mi * 16 + ln) * 4 + qd);
#pragma unroll
    for (int ni = 0; ni < 4; ++ni) pB[ni] = 1024 + chunk_swz((wnq + ni * 16 + ln) * 4 + qd);

    f32x4 acc[8][4];
    const f32x4 z4 = {0.f, 0.f, 0.f, 0.f};
#pragma unroll
    for (int mi = 0; mi < 8; ++mi)
#pragma unroll
        for (int ni = 0; ni < 4; ++ni) acc[mi][ni] = z4;

    const int NT = INTER / 32;  // 172 K-tiles
#pragma unroll
    for (int t = 0; t < 2; ++t)
#pragma unroll
        for (int p = 0; p < 2; ++p) {
            const int c = p * 512 + tid;
            async_copy16(aSrc[p] + t * 32, (void*)(S + (size_t)(t * 2048 + c) * 8));
            async_copy16(bSrc[p] + t * 32, (void*)(S + (size_t)(t * 2048 + 1024 + c) * 8));
        }

    for (int t = 0; t < NT; ++t) {
        const __hip_bfloat16* Sb = S + (size_t)((t & 3) * 2048) * 8;
        const int buf2 = ((t + 2) & 3) * 2048;
        const int k2 = (t + 2 < NT ? t + 2 : t + 2 - NT) * 32;

        // ---- phase 0 ----
        {
            const int c = tid;
            async_copy16(aSrc[0] + k2, (void*)(S + (size_t)(buf2 + c) * 8));
            async_copy16(bSrc[0] + k2, (void*)(S + (size_t)(buf2 + 1024 + c) * 8));
        }
        asm volatile("s_waitcnt vmcnt(6)" ::: "memory");
        block_barrier();

        bf16x8 bf_[4], af[4];
#pragma unroll
        for (int ni = 0; ni < 4; ++ni)
            bf_[ni] = *reinterpret_cast<const bf16x8*>(Sb + (size_t)pB[ni] * 8);
#pragma unroll
        for (int mi = 0; mi < 4; ++mi)
            af[mi] = *reinterpret_cast<const bf16x8*>(Sb + (size_t)pA[mi] * 8);

        __builtin_amdgcn_s_setprio(1);
#pragma unroll
        for (int mi = 0; mi < 4; ++mi)
#pragma unroll
            for (int ni = 0; ni < 4; ++ni)
                acc[mi][ni] = __builtin_amdgcn_mfma_f32_16x16x32_bf16(af[mi], bf_[ni], acc[mi][ni], 0, 0, 0);
        __builtin_amdgcn_s_setprio(0);
        block_barrier();

        // ---- phase 1 ----
        {
            const int c = 512 + tid;
            async_copy16(aSrc[1] + k2, (void*)(S + (size_t)(buf2 + c) * 8));
            async_copy16(bSrc[1] + k2, (void*)(S + (size_t)(buf2 + 1024 + c) * 8));
        }
        bf16x8 af2[4];
#pragma unroll
        for (int mi = 0; mi < 4; ++mi)
            af2[mi] = *reinterpret_cast<const bf16x8*>(Sb + (size_t)pA[mi + 4] * 8);

        __builtin_amdgcn_s_setprio(1);
#pragma unroll
        for (int mi = 0; mi < 4; ++mi)
#pragma unroll
            for (int ni = 0; ni < 4; ++ni)
                acc[mi + 4][ni] = __builtin_amdgcn_mfma_f32_16x16x32_bf16(af2[mi], bf_[ni], acc[mi + 4][ni], 0, 0, 0);
        __builtin_amdgcn_s_setprio(0);
        block_barrier();
    }

    float* O = out + (size_t)(e * TE + m0 + wmh) * HID + n0 + wnq;
#pragma unroll
    for (int mi = 0; mi < 8; ++mi)
#pragma unroll
        for (int ni = 0; ni < 4; ++ni)
#pragma unroll
            for (int r = 0; r < 4; ++r) {
                const int rr = mi * 16 + qd * 4 + r;
                const int cc = ni * 16 + ln;
                O[(size_t)rr * HID + cc] = acc[mi][ni][r];
            }
}

extern "C" void kernel_launch(void* const* d_in, const int* in_sizes, int n_in,
                              void* d_out, int out_size, void* d_ws, size_t ws_size,
                              hipStream_t stream) {
    const float* x = (const float*)d_in[0];
    const float* gw = (const float*)d_in[1];   // [E][HID][INTER]
    const float* uw = (const float*)d_in[2];   // [E][HID][INTER]
    const float* dw = (const float*)d_in[3];   // [E][INTER][HID]
    float* out = (float*)d_out;

    // workspace layout (bytes)
    const size_t XB_BYTES = (size_t)TOK * HID * 2;           // 67,108,864
    const size_t WT_BYTES = (size_t)NE * INTER * HID * 2;    // 180,355,072
    char* ws = (char*)d_ws;
    __hip_bfloat16* xb = (__hip_bfloat16*)(ws);
    __hip_bfloat16* gwt = (__hip_bfloat16*)(ws + XB_BYTES);
    __hip_bfloat16* uwt = (__hip_bfloat16*)(ws + XB_BYTES + WT_BYTES);
    __hip_bfloat16* hb = (__hip_bfloat16*)(ws + XB_BYTES + 2 * WT_BYTES);
    __hip_bfloat16* dwt = gwt;  // alias: down_w transposed after gemm1 consumed gwt

    // 1) cast x -> bf16
    cast_x_kernel<<<(TOK * HID) / (256 * 4), 256, 0, stream>>>(x, xb);
    // 2) transpose+cast gate/up: [HID][INTER] -> [INTER][HID]
    tcast2_kernel<<<dim3(INTER / 128, HID / 64, NE), 256, 0, stream>>>(gw, gwt, HID, INTER);
    tcast2_kernel<<<dim3(INTER / 128, HID / 64, NE), 256, 0, stream>>>(uw, uwt, HID, INTER);
    // 3) fused gate/up GEMM + SwiGLU -> h
    gemm1_swiglu_kernel<<<dim3(TE / 256, INTER / 128, NE), 512, 0, stream>>>(xb, gwt, uwt, hb);
    // 4) transpose+cast down: [INTER][HID] -> [HID][INTER] (into gwt region)
    tcast2_kernel<<<dim3(HID / 128, INTER / 64, NE), 256, 0, stream>>>(dw, dwt, INTER, HID);
    // 5) down GEMM -> fp32 out
    gemm2_kernel<<<dim3(TE / 256, HID / 256, NE), 512, 0, stream>>>(hb, dwt, out);
}